// Round 3
// baseline (454.606 us; speedup 1.0000x reference)
//
#include <hip/hip_runtime.h>

#define EPS 1e-5f
#define NTHR 256
#define NBLK 512
#define NSLOT 16

typedef __bf16 bf16x8 __attribute__((ext_vector_type(8)));
typedef float f32x16 __attribute__((ext_vector_type(16)));

// d_ws layout:
//   [0, N*16*2)                   bf16 copy of x, tile-major in MFMA B-frag order:
//                                 xb[(t*64 + lane)*8 .. +8) = 8 bf16 for (tile t, lane)
//   [N*16*2, +3*NSLOT*64*4)       stats slots: layer L: stats[L*NSLOT*64 + slot*64 + idx]
//                                 idx 0..31 = sum(z_L), 32..63 = sum(z_L^2)
//   [.. +8)                       grid barrier {count, generation}
//
// Layout algebra (m74/m101-verified 32x32x16 mappings):
//   C/D: col=lane&31 (data row), row p = (reg&3)+8*(reg>>2)+4h, h=lane>>5
//   A:   m=lane&31, k=8h+j ;  B: n=lane&31, k=8h+j
// Acc regs 0..7 / 8..15 feed the next layer's B-frag; next weights use columns
// permuted by phi(K)=(j&3)+8*(j>>2)+4h+16*kh (involution). BN scale a>0 folds
// into next-layer weight columns; shift e folds into the MFMA accumulator init.
//
// R3 change: single persistent kernel, 4 phases separated by a device-scope
// grid barrier. R1 (load depth) and R2 (atomic decontention) were both null
// -> per-instruction theories dead; remaining candidates are the 4
// launch/drain boundaries and zero cross-pass locality. Fixed tile ownership
// (wave g owns tiles [g*32,(g+1)*32) in all phases) means each block re-reads
// only xb bytes it wrote (no coherence hazard on plain loads, same-XCD L2
// locality); phases 2/4 traverse in reverse (serpentine) so chunk tails are
// L2-warm. Stats are the only cross-block data: device-scope atomicAdd on
// write, __hip_atomic_load(AGENT) on read. Co-residency: 512 blocks = 2/CU,
// __launch_bounds__(256,2) caps VGPR at 256 (2 waves/SIMD) and LDS is 1.5 KiB
// -> both blocks fit every CU.

__global__ __launch_bounds__(NTHR, 2) void k_all(
    const float* __restrict__ x, __bf16* __restrict__ xb,
    const float* __restrict__ W1, const float* __restrict__ b1,
    const float* __restrict__ g1, const float* __restrict__ be1,
    const float* __restrict__ W2, const float* __restrict__ b2,
    const float* __restrict__ g2, const float* __restrict__ be2,
    const float* __restrict__ W3, const float* __restrict__ b3,
    const float* __restrict__ g3, const float* __restrict__ be3,
    const float* __restrict__ W4, const float* __restrict__ b4,
    float* __restrict__ stats, unsigned* __restrict__ bar,
    float* __restrict__ out, int N)
{
    __shared__ float s_stat[64];
    __shared__ float s_a[32];
    __shared__ float s_e[32];
    __shared__ float s_w[NTHR / 64][64];

    const int tid = threadIdx.x;
    const int lane = tid & 63;
    const int h = lane >> 5;
    const int ml = lane & 31;
    const float invN = 1.0f / (float)N;

    const int ntiles = N >> 5;
    const int nwaves = NBLK * (NTHR / 64);
    const int gwave  = blockIdx.x * (NTHR / 64) + (tid >> 6);
    const int tpw    = (ntiles + nwaves - 1) / nwaves;
    const int t0     = gwave * tpw;
    const int tend   = (t0 + tpw < ntiles) ? (t0 + tpw) : ntiles;
    const int cnt    = (tend > t0) ? (tend - t0) : 0;

    // ---- device-scope grid barrier (sense via monotone generation) ----
    auto gbar = [&](unsigned target) {
        __syncthreads();
        if (tid == 0) {
            __threadfence();
            unsigned old = __hip_atomic_fetch_add(&bar[0], 1u, __ATOMIC_ACQ_REL, __HIP_MEMORY_SCOPE_AGENT);
            if (old == (unsigned)(NBLK - 1)) {
                __hip_atomic_store(&bar[0], 0u, __ATOMIC_RELAXED, __HIP_MEMORY_SCOPE_AGENT);
                __hip_atomic_fetch_add(&bar[1], 1u, __ATOMIC_RELEASE, __HIP_MEMORY_SCOPE_AGENT);
            } else {
                while (__hip_atomic_load(&bar[1], __ATOMIC_ACQUIRE, __HIP_MEMORY_SCOPE_AGENT) < target)
                    __builtin_amdgcn_s_sleep(2);
            }
        }
        __syncthreads();
    };

    // ---- combine stats slots for layer L, derive BN scale a / shift e ----
    auto derive = [&](int L, const float* g, const float* be, const float* b) {
        if (tid < 64) {
            float a = 0.f;
            #pragma unroll
            for (int s = 0; s < NSLOT; ++s)
                a += __hip_atomic_load(&stats[L * (NSLOT * 64) + s * 64 + tid],
                                       __ATOMIC_RELAXED, __HIP_MEMORY_SCOPE_AGENT);
            s_stat[tid] = a;
        }
        __syncthreads();
        if (tid < 32) {
            float mu = s_stat[tid] * invN;
            float v  = s_stat[32 + tid] * invN - mu * mu;
            float a  = g[tid] * rsqrtf(v + EPS);
            s_a[tid] = a;
            s_e[tid] = b[tid] - mu + be[tid] / a;
        }
        __syncthreads();
    };

    float sums[16], sqs[16];

    // ---- block-reduce per-wave stats, one atomic per feature per block ----
    auto flush_stats = [&](int L) {
        const int wid = tid >> 6;
        #pragma unroll
        for (int i = 0; i < 16; ++i) {
            float s = sums[i], q = sqs[i];
            #pragma unroll
            for (int d = 1; d <= 16; d <<= 1) {
                s += __shfl_xor(s, d);
                q += __shfl_xor(q, d);
            }
            if (ml == 0) {
                int p = (i & 3) + 8 * (i >> 2) + 4 * h;
                s_w[wid][p] = s;
                s_w[wid][32 + p] = q;
            }
        }
        __syncthreads();
        if (tid < 64) {
            float a = s_w[0][tid] + s_w[1][tid] + s_w[2][tid] + s_w[3][tid];
            atomicAdd(&stats[L * (NSLOT * 64) + (blockIdx.x & (NSLOT - 1)) * 64 + tid], a);
        }
    };

    // ---- persistent fragments ----
    bf16x8 w1f;
    {
        const float* p = W1 + ml * 16 + h * 8;
        #pragma unroll
        for (int j = 0; j < 8; ++j) w1f[j] = (__bf16)p[j];
    }
    f32x16 c1;
    #pragma unroll
    for (int i = 0; i < 16; ++i) {
        int p = (i & 3) + 8 * (i >> 2) + 4 * h;
        c1[i] = b1[p];
    }

    // ================= phase 1: stage xb, stats of z1 =================
    #pragma unroll
    for (int i = 0; i < 16; ++i) { sums[i] = 0.f; sqs[i] = 0.f; }
    for (int i0 = 0; i0 < cnt; i0 += 4) {
        float4 u0[4], u1[4];
        #pragma unroll
        for (int k = 0; k < 4; ++k) {
            int i = i0 + k;
            if (i < cnt) {
                int row = ((t0 + i) << 5) + ml;
                const float4* xp = (const float4*)(x + (size_t)row * 16 + h * 8);
                u0[k] = xp[0]; u1[k] = xp[1];
            }
        }
        #pragma unroll
        for (int k = 0; k < 4; ++k) {
            int i = i0 + k;
            if (i < cnt) {
                int t = t0 + i;
                bf16x8 xf;
                xf[0] = (__bf16)u0[k].x; xf[1] = (__bf16)u0[k].y;
                xf[2] = (__bf16)u0[k].z; xf[3] = (__bf16)u0[k].w;
                xf[4] = (__bf16)u1[k].x; xf[5] = (__bf16)u1[k].y;
                xf[6] = (__bf16)u1[k].z; xf[7] = (__bf16)u1[k].w;
                *(bf16x8*)(xb + ((size_t)t * 64 + lane) * 8) = xf;
                f32x16 a1 = __builtin_amdgcn_mfma_f32_32x32x16_bf16(w1f, xf, c1, 0, 0, 0);
                #pragma unroll
                for (int q = 0; q < 16; ++q) { sums[q] += a1[q]; sqs[q] = fmaf(a1[q], a1[q], sqs[q]); }
            }
        }
    }
    flush_stats(0);
    gbar(1);

    // ================= phase 2: stats of z2 (reverse traversal) =================
    derive(0, g1, be1, b1);
    #pragma unroll
    for (int i = 0; i < 16; ++i) {
        int p = (i & 3) + 8 * (i >> 2) + 4 * h;
        c1[i] = s_e[p];
    }
    bf16x8 w2f0, w2f1;
    #pragma unroll
    for (int kh = 0; kh < 2; ++kh)
        #pragma unroll
        for (int j = 0; j < 8; ++j) {
            int pk = (j & 3) + 8 * (j >> 2) + 4 * h + 16 * kh;
            float v = W2[ml * 32 + pk] * s_a[pk];
            if (kh == 0) w2f0[j] = (__bf16)v; else w2f1[j] = (__bf16)v;
        }
    f32x16 c2;
    #pragma unroll
    for (int i = 0; i < 16; ++i) {
        int p = (i & 3) + 8 * (i >> 2) + 4 * h;
        c2[i] = b2[p];
    }
    #pragma unroll
    for (int i = 0; i < 16; ++i) { sums[i] = 0.f; sqs[i] = 0.f; }
    for (int i0 = 0; i0 < cnt; i0 += 4) {
        bf16x8 xf[4];
        #pragma unroll
        for (int k = 0; k < 4; ++k) {
            int i = i0 + k;
            if (i < cnt) {
                int t = tend - 1 - i;
                xf[k] = *(const bf16x8*)(xb + ((size_t)t * 64 + lane) * 8);
            }
        }
        #pragma unroll
        for (int k = 0; k < 4; ++k) {
            int i = i0 + k;
            if (i < cnt) {
                f32x16 a1 = __builtin_amdgcn_mfma_f32_32x32x16_bf16(w1f, xf[k], c1, 0, 0, 0);
                bf16x8 qa, qb;
                #pragma unroll
                for (int j = 0; j < 8; ++j) {
                    qa[j] = (__bf16)fmaxf(a1[j], 0.f);
                    qb[j] = (__bf16)fmaxf(a1[8 + j], 0.f);
                }
                f32x16 a2 = __builtin_amdgcn_mfma_f32_32x32x16_bf16(w2f0, qa, c2, 0, 0, 0);
                a2 = __builtin_amdgcn_mfma_f32_32x32x16_bf16(w2f1, qb, a2, 0, 0, 0);
                #pragma unroll
                for (int q = 0; q < 16; ++q) { sums[q] += a2[q]; sqs[q] = fmaf(a2[q], a2[q], sqs[q]); }
            }
        }
    }
    flush_stats(1);
    gbar(2);

    // ================= phase 3: stats of z3 (forward) =================
    derive(1, g2, be2, b2);
    #pragma unroll
    for (int i = 0; i < 16; ++i) {
        int p = (i & 3) + 8 * (i >> 2) + 4 * h;
        c2[i] = s_e[p];
    }
    bf16x8 w3f0, w3f1;
    #pragma unroll
    for (int kh = 0; kh < 2; ++kh)
        #pragma unroll
        for (int j = 0; j < 8; ++j) {
            int pk = (j & 3) + 8 * (j >> 2) + 4 * h + 16 * kh;
            float v = W3[ml * 32 + pk] * s_a[pk];
            if (kh == 0) w3f0[j] = (__bf16)v; else w3f1[j] = (__bf16)v;
        }
    f32x16 c3;
    #pragma unroll
    for (int i = 0; i < 16; ++i) {
        int p = (i & 3) + 8 * (i >> 2) + 4 * h;
        c3[i] = b3[p];
    }
    #pragma unroll
    for (int i = 0; i < 16; ++i) { sums[i] = 0.f; sqs[i] = 0.f; }
    for (int i0 = 0; i0 < cnt; i0 += 4) {
        bf16x8 xf[4];
        #pragma unroll
        for (int k = 0; k < 4; ++k) {
            int i = i0 + k;
            if (i < cnt) {
                int t = t0 + i;
                xf[k] = *(const bf16x8*)(xb + ((size_t)t * 64 + lane) * 8);
            }
        }
        #pragma unroll
        for (int k = 0; k < 4; ++k) {
            int i = i0 + k;
            if (i < cnt) {
                f32x16 a1 = __builtin_amdgcn_mfma_f32_32x32x16_bf16(w1f, xf[k], c1, 0, 0, 0);
                bf16x8 qa, qb;
                #pragma unroll
                for (int j = 0; j < 8; ++j) {
                    qa[j] = (__bf16)fmaxf(a1[j], 0.f);
                    qb[j] = (__bf16)fmaxf(a1[8 + j], 0.f);
                }
                f32x16 a2 = __builtin_amdgcn_mfma_f32_32x32x16_bf16(w2f0, qa, c2, 0, 0, 0);
                a2 = __builtin_amdgcn_mfma_f32_32x32x16_bf16(w2f1, qb, a2, 0, 0, 0);
                bf16x8 pa, pb;
                #pragma unroll
                for (int j = 0; j < 8; ++j) {
                    pa[j] = (__bf16)fmaxf(a2[j], 0.f);
                    pb[j] = (__bf16)fmaxf(a2[8 + j], 0.f);
                }
                f32x16 a3 = __builtin_amdgcn_mfma_f32_32x32x16_bf16(w3f0, pa, c3, 0, 0, 0);
                a3 = __builtin_amdgcn_mfma_f32_32x32x16_bf16(w3f1, pb, a3, 0, 0, 0);
                #pragma unroll
                for (int q = 0; q < 16; ++q) { sums[q] += a3[q]; sqs[q] = fmaf(a3[q], a3[q], sqs[q]); }
            }
        }
    }
    flush_stats(2);
    gbar(3);

    // ================= phase 4: output (reverse traversal) =================
    derive(2, g3, be3, b3);
    #pragma unroll
    for (int i = 0; i < 16; ++i) {
        int p = (i & 3) + 8 * (i >> 2) + 4 * h;
        c3[i] = s_e[p];
    }
    float w4c[16];
    #pragma unroll
    for (int i = 0; i < 16; ++i) {
        int p = (i & 3) + 8 * (i >> 2) + 4 * h;
        w4c[i] = W4[p] * s_a[p];
    }
    const float b4v = b4[0];
    for (int i0 = 0; i0 < cnt; i0 += 4) {
        bf16x8 xf[4];
        #pragma unroll
        for (int k = 0; k < 4; ++k) {
            int i = i0 + k;
            if (i < cnt) {
                int t = tend - 1 - i;
                xf[k] = *(const bf16x8*)(xb + ((size_t)t * 64 + lane) * 8);
            }
        }
        #pragma unroll
        for (int k = 0; k < 4; ++k) {
            int i = i0 + k;
            if (i < cnt) {
                int t = tend - 1 - i;
                f32x16 a1 = __builtin_amdgcn_mfma_f32_32x32x16_bf16(w1f, xf[k], c1, 0, 0, 0);
                bf16x8 qa, qb;
                #pragma unroll
                for (int j = 0; j < 8; ++j) {
                    qa[j] = (__bf16)fmaxf(a1[j], 0.f);
                    qb[j] = (__bf16)fmaxf(a1[8 + j], 0.f);
                }
                f32x16 a2 = __builtin_amdgcn_mfma_f32_32x32x16_bf16(w2f0, qa, c2, 0, 0, 0);
                a2 = __builtin_amdgcn_mfma_f32_32x32x16_bf16(w2f1, qb, a2, 0, 0, 0);
                bf16x8 pa, pb;
                #pragma unroll
                for (int j = 0; j < 8; ++j) {
                    pa[j] = (__bf16)fmaxf(a2[j], 0.f);
                    pb[j] = (__bf16)fmaxf(a2[8 + j], 0.f);
                }
                f32x16 a3 = __builtin_amdgcn_mfma_f32_32x32x16_bf16(w3f0, pa, c3, 0, 0, 0);
                a3 = __builtin_amdgcn_mfma_f32_32x32x16_bf16(w3f1, pb, a3, 0, 0, 0);
                float o = 0.f;
                #pragma unroll
                for (int q = 0; q < 16; ++q) o = fmaf(w4c[q], fmaxf(a3[q], 0.f), o);
                o += __shfl_xor(o, 32);
                if (h == 0) out[(t << 5) + ml] = o + b4v;
            }
        }
    }
}

extern "C" void kernel_launch(void* const* d_in, const int* in_sizes, int n_in,
                              void* d_out, int out_size, void* d_ws, size_t ws_size,
                              hipStream_t stream) {
    const float* x   = (const float*)d_in[0];
    const float* W1  = (const float*)d_in[1];
    const float* b1  = (const float*)d_in[2];
    const float* g1  = (const float*)d_in[3];
    const float* be1 = (const float*)d_in[4];
    const float* W2  = (const float*)d_in[5];
    const float* b2  = (const float*)d_in[6];
    const float* g2  = (const float*)d_in[7];
    const float* be2 = (const float*)d_in[8];
    const float* W3  = (const float*)d_in[9];
    const float* b3  = (const float*)d_in[10];
    const float* g3  = (const float*)d_in[11];
    const float* be3 = (const float*)d_in[12];
    const float* W4  = (const float*)d_in[13];
    const float* b4  = (const float*)d_in[14];
    float* out = (float*)d_out;
    int N = in_sizes[0] / 16;

    __bf16* xb    = (__bf16*)d_ws;
    float* stats  = (float*)((char*)d_ws + (size_t)N * 16 * 2);
    unsigned* bar = (unsigned*)((char*)stats + 3 * NSLOT * 64 * sizeof(float));

    // zero stats slots + barrier {count, gen}
    hipMemsetAsync(stats, 0, 3 * NSLOT * 64 * sizeof(float) + 64, stream);

    k_all<<<NBLK, NTHR, 0, stream>>>(x, xb, W1, b1, g1, be1, W2, b2, g2, be2,
                                     W3, b3, g3, be3, W4, b4, stats, bar, out, N);
}